// Round 1
// baseline (2205.628 us; speedup 1.0000x reference)
//
#include <hip/hip_runtime.h>

typedef unsigned short u16;
typedef __attribute__((ext_vector_type(8))) short short8;
typedef __attribute__((ext_vector_type(4))) float floatx4;

#define D_MODEL 1024
#define NHEADS 16
#define HD 64
#define BATCH 2
#define SEQ 2048
#define MROWS (BATCH * SEQ)  // 4096

static __device__ __forceinline__ u16 f2bf(float f) {
  unsigned int u = __float_as_uint(f);
  u += 0x7fffu + ((u >> 16) & 1u);  // round-to-nearest-even
  return (u16)(u >> 16);
}

// ---------------- fp32 -> bf16 convert (vectorized x4) ----------------
__global__ void cvt_kernel(const float* __restrict__ src, u16* __restrict__ dst, int n4) {
  int i = blockIdx.x * 256 + threadIdx.x;
  if (i < n4) {
    float4 v = ((const float4*)src)[i];
    ushort4 o;
    o.x = f2bf(v.x); o.y = f2bf(v.y); o.z = f2bf(v.z); o.w = f2bf(v.w);
    ((ushort4*)dst)[i] = o;
  }
}

// ---------------- bf16 MFMA NT-GEMM: C[M,N] = A[M,K] * B[N,K]^T ----------------
// MODE 0: plain fp32 store to o0[M,N]
// MODE 1: QKV scatter: n -> (tensor, head, dim); m -> (b, s); write [B,H,S,HD] fp32
template <int MODE>
__global__ __launch_bounds__(256) void gemm_bf16_nt(
    const u16* __restrict__ A, const u16* __restrict__ B, float* __restrict__ o0,
    float* __restrict__ o1, float* __restrict__ o2, int M, int N, int K) {
  __shared__ u16 As[128][40];  // +8 pad: 80B row stride -> 2-way max on frag reads
  __shared__ u16 Bs[128][40];
  const int t = threadIdx.x;
  const int lane = t & 63;
  const int wv = t >> 6;
  const int wr = wv >> 1, wc = wv & 1;  // wave covers 64x64 quadrant
  const int m0 = blockIdx.y * 128, n0 = blockIdx.x * 128;
  const int qd = lane >> 4, lr = lane & 15;
  const int srow = t >> 2;         // staging row 0..63 (+64 on pass 2)
  const int scol = (t & 3) * 8;    // staging col (8 bf16 = 16B)

  floatx4 acc[4][4];
#pragma unroll
  for (int i = 0; i < 4; ++i)
#pragma unroll
    for (int j = 0; j < 4; ++j) acc[i][j] = (floatx4){0.f, 0.f, 0.f, 0.f};

  uint4 aReg[2], bReg[2];
#pragma unroll
  for (int p = 0; p < 2; ++p) {
    aReg[p] = *(const uint4*)&A[(size_t)(m0 + srow + p * 64) * K + scol];
    bReg[p] = *(const uint4*)&B[(size_t)(n0 + srow + p * 64) * K + scol];
  }

  for (int kt = 0; kt < K; kt += 32) {
    __syncthreads();
#pragma unroll
    for (int p = 0; p < 2; ++p) {
      *(uint4*)&As[srow + p * 64][scol] = aReg[p];
      *(uint4*)&Bs[srow + p * 64][scol] = bReg[p];
    }
    __syncthreads();
    short8 af[4], bfr[4];
#pragma unroll
    for (int i = 0; i < 4; ++i)
      af[i] = *(const short8*)&As[wr * 64 + i * 16 + lr][qd * 8];
#pragma unroll
    for (int j = 0; j < 4; ++j)
      bfr[j] = *(const short8*)&Bs[wc * 64 + j * 16 + lr][qd * 8];
    if (kt + 32 < K) {  // prefetch next K-slab, overlaps MFMA
      const int k2 = kt + 32;
#pragma unroll
      for (int p = 0; p < 2; ++p) {
        aReg[p] = *(const uint4*)&A[(size_t)(m0 + srow + p * 64) * K + k2 + scol];
        bReg[p] = *(const uint4*)&B[(size_t)(n0 + srow + p * 64) * K + k2 + scol];
      }
    }
#pragma unroll
    for (int i = 0; i < 4; ++i)
#pragma unroll
      for (int j = 0; j < 4; ++j)
        acc[i][j] = __builtin_amdgcn_mfma_f32_16x16x32_bf16(af[i], bfr[j], acc[i][j], 0, 0, 0);
  }

#pragma unroll
  for (int i = 0; i < 4; ++i) {
#pragma unroll
    for (int j = 0; j < 4; ++j) {
      const int n = n0 + wc * 64 + j * 16 + lr;
#pragma unroll
      for (int r = 0; r < 4; ++r) {
        const int m = m0 + wr * 64 + i * 16 + qd * 4 + r;  // C/D: col=lane&15, row=(lane>>4)*4+reg
        const float v = acc[i][j][r];
        if (MODE == 0) {
          o0[(size_t)m * N + n] = v;
        } else {
          const int tn = n >> 10, nn = n & 1023;
          const int h = nn >> 6, d = nn & 63;
          const int b = m >> 11, s = m & 2047;
          float* dst = (tn == 0) ? o0 : ((tn == 1) ? o1 : o2);
          dst[((size_t)(b * NHEADS + h) * SEQ + s) * HD + d] = v;
        }
      }
    }
  }
}

// ---------------- RoPE in-place on [B,H,S,HD] fp32; one wave per row ----------------
__global__ void rope_kernel(float* __restrict__ q, float* __restrict__ k) {
  const int rid = blockIdx.x * 4 + (threadIdx.x >> 6);  // 0..131071 (q rows then k rows)
  const int lane = threadIdx.x & 63;
  float* base = (rid < 65536) ? q : k;
  const int r = rid & 65535;
  const int s = r & (SEQ - 1);
  float* p = base + (size_t)r * HD + lane;
  const int fi = lane & 31;
  const float inv = expf(-(float)fi * 0.28782313662425574f);  // ln(10000)/32
  const float th = (float)s * inv;
  const float c = cosf(th), sn = sinf(th);
  const float v = *p;
  const float pv = __shfl_xor(v, 32, 64);  // partner d^32 within the wave
  *p = v * c + ((lane < 32) ? -pv : pv) * sn;
}

// ---------------- causal flash attention, fp32, 64x64 tiles ----------------
// grid: (qtile=32, bh=32); block 256. Writes O as bf16 in [B,S,H*HD] layout.
__global__ __launch_bounds__(256) void flash_kernel(
    const float* __restrict__ Q, const float* __restrict__ K,
    const float* __restrict__ V, u16* __restrict__ O) {
  __shared__ float Qs[64][68];
  __shared__ float Ks[64][68];
  __shared__ float Vs[64][68];
  __shared__ float Ps[64][68];
  const int t = threadIdx.x;
  const int tx = t & 15, ty = t >> 4;
  const int qt = blockIdx.x;
  const int bh = blockIdx.y;
  const int q0 = qt * 64;
  const size_t base = (size_t)bh * SEQ * HD;

#pragma unroll
  for (int p = 0; p < 4; ++p) {  // Q tile, 1/sqrt(HD) folded in
    int idx = p * 256 + t;
    int row = idx >> 4, c4 = (idx & 15) * 4;
    float4 v = *(const float4*)&Q[base + (size_t)(q0 + row) * HD + c4];
    v.x *= 0.125f; v.y *= 0.125f; v.z *= 0.125f; v.w *= 0.125f;
    *(float4*)&Qs[row][c4] = v;
  }

  float m_i[4], l_i[4], oacc[4][4];
#pragma unroll
  for (int i = 0; i < 4; ++i) {
    m_i[i] = -1e30f; l_i[i] = 0.f;
#pragma unroll
    for (int jj = 0; jj < 4; ++jj) oacc[i][jj] = 0.f;
  }

  for (int jt = 0; jt <= qt; ++jt) {
    const int k0 = jt * 64;
    __syncthreads();  // protect Ks/Vs/Ps from prev iteration's readers
#pragma unroll
    for (int p = 0; p < 4; ++p) {
      int idx = p * 256 + t;
      int row = idx >> 4, c4 = (idx & 15) * 4;
      *(float4*)&Ks[row][c4] = *(const float4*)&K[base + (size_t)(k0 + row) * HD + c4];
      *(float4*)&Vs[row][c4] = *(const float4*)&V[base + (size_t)(k0 + row) * HD + c4];
    }
    __syncthreads();

    // S = Qs * Ks^T; rows ty+16i, cols tx+16j (strided -> 2-way max bank aliasing)
    float sv[4][4];
#pragma unroll
    for (int i = 0; i < 4; ++i)
#pragma unroll
      for (int jj = 0; jj < 4; ++jj) sv[i][jj] = 0.f;
    for (int d4 = 0; d4 < 16; ++d4) {
      float4 qv[4], kv[4];
#pragma unroll
      for (int i = 0; i < 4; ++i) qv[i] = *(const float4*)&Qs[ty + 16 * i][d4 * 4];
#pragma unroll
      for (int jj = 0; jj < 4; ++jj) kv[jj] = *(const float4*)&Ks[tx + 16 * jj][d4 * 4];
#pragma unroll
      for (int i = 0; i < 4; ++i)
#pragma unroll
        for (int jj = 0; jj < 4; ++jj) {
          sv[i][jj] = fmaf(qv[i].x, kv[jj].x, sv[i][jj]);
          sv[i][jj] = fmaf(qv[i].y, kv[jj].y, sv[i][jj]);
          sv[i][jj] = fmaf(qv[i].z, kv[jj].z, sv[i][jj]);
          sv[i][jj] = fmaf(qv[i].w, kv[jj].w, sv[i][jj]);
        }
    }

    if (jt == qt) {  // causal mask on diagonal tile only
#pragma unroll
      for (int i = 0; i < 4; ++i)
#pragma unroll
        for (int jj = 0; jj < 4; ++jj)
          if (tx + 16 * jj > ty + 16 * i) sv[i][jj] = -1e30f;
    }

#pragma unroll
    for (int i = 0; i < 4; ++i) {
      float rm = fmaxf(fmaxf(sv[i][0], sv[i][1]), fmaxf(sv[i][2], sv[i][3]));
      rm = fmaxf(rm, __shfl_xor(rm, 1, 64));
      rm = fmaxf(rm, __shfl_xor(rm, 2, 64));
      rm = fmaxf(rm, __shfl_xor(rm, 4, 64));
      rm = fmaxf(rm, __shfl_xor(rm, 8, 64));
      const float mn = fmaxf(m_i[i], rm);
      const float alpha = __expf(m_i[i] - mn);
      m_i[i] = mn;
      float rs = 0.f;
#pragma unroll
      for (int jj = 0; jj < 4; ++jj) {
        const float pp = __expf(sv[i][jj] - mn);
        Ps[ty + 16 * i][tx + 16 * jj] = pp;
        rs += pp;
      }
      rs += __shfl_xor(rs, 1, 64);
      rs += __shfl_xor(rs, 2, 64);
      rs += __shfl_xor(rs, 4, 64);
      rs += __shfl_xor(rs, 8, 64);
      l_i[i] = l_i[i] * alpha + rs;
#pragma unroll
      for (int jj = 0; jj < 4; ++jj) oacc[i][jj] *= alpha;
    }
    __syncthreads();  // Ps visible before PV

    for (int kk = 0; kk < 64; ++kk) {
      const float4 vv = *(const float4*)&Vs[kk][tx * 4];
#pragma unroll
      for (int i = 0; i < 4; ++i) {
        const float pp = Ps[ty + 16 * i][kk];
        oacc[i][0] = fmaf(pp, vv.x, oacc[i][0]);
        oacc[i][1] = fmaf(pp, vv.y, oacc[i][1]);
        oacc[i][2] = fmaf(pp, vv.z, oacc[i][2]);
        oacc[i][3] = fmaf(pp, vv.w, oacc[i][3]);
      }
    }
  }

  const int b = bh >> 4, h = bh & 15;
#pragma unroll
  for (int i = 0; i < 4; ++i) {
    const float invl = 1.f / l_i[i];
    const int s = q0 + ty + 16 * i;
    const size_t off = ((size_t)(b * SEQ + s) * D_MODEL) + h * HD + tx * 4;
    ushort4 o;
    o.x = f2bf(oacc[i][0] * invl);
    o.y = f2bf(oacc[i][1] * invl);
    o.z = f2bf(oacc[i][2] * invl);
    o.w = f2bf(oacc[i][3] * invl);
    *(ushort4*)&O[off] = o;
  }
}

extern "C" void kernel_launch(void* const* d_in, const int* in_sizes, int n_in,
                              void* d_out, int out_size, void* d_ws, size_t ws_size,
                              hipStream_t stream) {
  const float* x  = (const float*)d_in[0];
  const float* Wq = (const float*)d_in[1];
  const float* Wk = (const float*)d_in[2];
  const float* Wv = (const float*)d_in[3];
  const float* Wo = (const float*)d_in[4];
  float* out = (float*)d_out;

  // workspace layout (72 MB total)
  u16* xb = (u16*)d_ws;           // x as bf16            [4096,1024]
  u16* wqkv = xb + 4194304;       // Wq|Wk|Wv bf16        [3072,1024]
  u16* wo = wqkv + 3145728;       // Wo bf16              [1024,1024]
  float* qw = (float*)(wo + 1048576);  // Q fp32          [B,H,S,HD]
  float* kw = qw + 4194304;            // K fp32
  float* vw = kw + 4194304;            // V fp32
  u16* ow = (u16*)(vw + 4194304);      // O bf16          [B,S,H*HD]

  cvt_kernel<<<4096, 256, 0, stream>>>(x, xb, 1048576);
  cvt_kernel<<<1024, 256, 0, stream>>>(Wq, wqkv, 262144);
  cvt_kernel<<<1024, 256, 0, stream>>>(Wk, wqkv + 1048576, 262144);
  cvt_kernel<<<1024, 256, 0, stream>>>(Wv, wqkv + 2097152, 262144);
  cvt_kernel<<<1024, 256, 0, stream>>>(Wo, wo, 262144);

  gemm_bf16_nt<1><<<dim3(24, 32), 256, 0, stream>>>(xb, wqkv, qw, kw, vw, MROWS, 3072, 1024);
  rope_kernel<<<32768, 256, 0, stream>>>(qw, kw);
  flash_kernel<<<dim3(32, 32), 256, 0, stream>>>(qw, kw, vw, ow);
  gemm_bf16_nt<0><<<dim3(8, 32), 256, 0, stream>>>(ow, wo, out, nullptr, nullptr, MROWS, 1024, 1024);
}

// Round 2
// 374.975 us; speedup vs baseline: 5.8821x; 5.8821x over previous
//
#include <hip/hip_runtime.h>

typedef unsigned short u16;
typedef __attribute__((ext_vector_type(8))) short short8;
typedef __attribute__((ext_vector_type(4))) float floatx4;

#define D_MODEL 1024
#define NHEADS 16
#define HD 64
#define BATCH 2
#define SEQ 2048
#define MROWS (BATCH * SEQ)  // 4096

static __device__ __forceinline__ u16 f2bf(float f) {
  unsigned int u = __float_as_uint(f);
  u += 0x7fffu + ((u >> 16) & 1u);  // round-to-nearest-even
  return (u16)(u >> 16);
}
static __device__ __forceinline__ float bf2f(u16 u) {
  return __uint_as_float(((unsigned int)u) << 16);
}

// ---------------- fp32 -> bf16 convert (vectorized x4) ----------------
__global__ void cvt_kernel(const float* __restrict__ src, u16* __restrict__ dst, int n4) {
  int i = blockIdx.x * 256 + threadIdx.x;
  if (i < n4) {
    float4 v = ((const float4*)src)[i];
    ushort4 o;
    o.x = f2bf(v.x); o.y = f2bf(v.y); o.z = f2bf(v.z); o.w = f2bf(v.w);
    ((ushort4*)dst)[i] = o;
  }
}

// ---------------- bf16 MFMA NT-GEMM: C[M,N] = A[M,K] * B[N,K]^T ----------------
// MODE 0: plain fp32 store to fo[M,N]
// MODE 1: QKV scatter (bf16): Q,K -> [B,H,S,HD]; V -> [B,H,HD,S] (transposed)
template <int MODE>
__global__ __launch_bounds__(256) void gemm_bf16_nt(
    const u16* __restrict__ A, const u16* __restrict__ B, float* __restrict__ fo,
    u16* __restrict__ qb, u16* __restrict__ kb, u16* __restrict__ vb,
    int M, int N, int K) {
  __shared__ u16 As[128][40];  // +8 pad
  __shared__ u16 Bs[128][40];
  const int t = threadIdx.x;
  const int lane = t & 63;
  const int wv = t >> 6;
  const int wr = wv >> 1, wc = wv & 1;  // wave covers 64x64 quadrant
  const int m0 = blockIdx.y * 128, n0 = blockIdx.x * 128;
  const int qd = lane >> 4, lr = lane & 15;
  const int srow = t >> 2;
  const int scol = (t & 3) * 8;

  floatx4 acc[4][4];
#pragma unroll
  for (int i = 0; i < 4; ++i)
#pragma unroll
    for (int j = 0; j < 4; ++j) acc[i][j] = (floatx4){0.f, 0.f, 0.f, 0.f};

  uint4 aReg[2], bReg[2];
#pragma unroll
  for (int p = 0; p < 2; ++p) {
    aReg[p] = *(const uint4*)&A[(size_t)(m0 + srow + p * 64) * K + scol];
    bReg[p] = *(const uint4*)&B[(size_t)(n0 + srow + p * 64) * K + scol];
  }

  for (int kt = 0; kt < K; kt += 32) {
    __syncthreads();
#pragma unroll
    for (int p = 0; p < 2; ++p) {
      *(uint4*)&As[srow + p * 64][scol] = aReg[p];
      *(uint4*)&Bs[srow + p * 64][scol] = bReg[p];
    }
    __syncthreads();
    short8 af[4], bfr[4];
#pragma unroll
    for (int i = 0; i < 4; ++i)
      af[i] = *(const short8*)&As[wr * 64 + i * 16 + lr][qd * 8];
#pragma unroll
    for (int j = 0; j < 4; ++j)
      bfr[j] = *(const short8*)&Bs[wc * 64 + j * 16 + lr][qd * 8];
    if (kt + 32 < K) {
      const int k2 = kt + 32;
#pragma unroll
      for (int p = 0; p < 2; ++p) {
        aReg[p] = *(const uint4*)&A[(size_t)(m0 + srow + p * 64) * K + k2 + scol];
        bReg[p] = *(const uint4*)&B[(size_t)(n0 + srow + p * 64) * K + k2 + scol];
      }
    }
#pragma unroll
    for (int i = 0; i < 4; ++i)
#pragma unroll
      for (int j = 0; j < 4; ++j)
        acc[i][j] = __builtin_amdgcn_mfma_f32_16x16x32_bf16(af[i], bfr[j], acc[i][j], 0, 0, 0);
  }

#pragma unroll
  for (int i = 0; i < 4; ++i) {
#pragma unroll
    for (int j = 0; j < 4; ++j) {
      const int n = n0 + wc * 64 + j * 16 + lr;
#pragma unroll
      for (int r = 0; r < 4; ++r) {
        const int m = m0 + wr * 64 + i * 16 + qd * 4 + r;  // C/D: col=lane&15, row=quad*4+reg
        const float v = acc[i][j][r];
        if (MODE == 0) {
          fo[(size_t)m * N + n] = v;
        } else {
          const int tn = n >> 10, nn = n & 1023;
          const int h = nn >> 6, d = nn & 63;
          const int b = m >> 11, s = m & 2047;
          const u16 val = f2bf(v);
          const size_t bh = (size_t)(b * NHEADS + h);
          if (tn == 0) qb[(bh * SEQ + s) * HD + d] = val;
          else if (tn == 1) kb[(bh * SEQ + s) * HD + d] = val;
          else vb[(bh * HD + d) * SEQ + s] = val;
        }
      }
    }
  }
}

// ---------------- RoPE in-place on bf16 [B,H,S,HD]; one wave per row ----------------
// Q rows additionally scaled by 1/sqrt(HD) = 0.125
__global__ void rope_kernel(u16* __restrict__ qb, u16* __restrict__ kb) {
  const int rid = blockIdx.x * 4 + (threadIdx.x >> 6);  // 0..131071
  const int lane = threadIdx.x & 63;
  u16* base = (rid < 65536) ? qb : kb;
  const float scale = (rid < 65536) ? 0.125f : 1.0f;
  const int r = rid & 65535;
  const int s = r & (SEQ - 1);
  u16* p = base + (size_t)r * HD + lane;
  const int fi = lane & 31;
  const float inv = expf(-(float)fi * 0.28782313662425574f);  // 10000^(-fi/32)
  const float th = (float)s * inv;
  float sn, c;
  sincosf(th, &sn, &c);
  const float v = bf2f(*p);
  const float pv = __shfl_xor(v, 32, 64);  // partner d^32 within the wave
  *p = f2bf((v * c + ((lane < 32) ? -pv : pv) * sn) * scale);
}

// ---------------- causal flash attention, bf16 MFMA ----------------
// grid: (pair=16, bh=32); block 256 (4 waves). Block p handles q-tiles p and 31-p
// (64 rows each) -> exactly 33 k-tile iterations per block, perfectly balanced.
// Q,K: [B,H,S,HD] bf16 (rope'd, Q pre-scaled). V: [B,H,HD,S] bf16 (transposed).
// O: [B,S,D_MODEL] bf16.
__global__ __launch_bounds__(256, 2) void flash_mfma(
    const u16* __restrict__ Q, const u16* __restrict__ Kg,
    const u16* __restrict__ Vg, u16* __restrict__ O) {
  __shared__ u16 Ks[64][72];      // [key][hd]
  __shared__ u16 Vs[64][72];      // [hd][key] (global already transposed)
  __shared__ u16 Ps[4][16][72];   // per-wave P tile [qrow][key]
  const int t = threadIdx.x;
  const int lane = t & 63, wv = t >> 6;
  const int lr = lane & 15, qd = lane >> 4;
  const int bh = blockIdx.y;
  const int pr = blockIdx.x;
  const size_t baseQK = (size_t)bh * SEQ * HD;
  const size_t baseV = (size_t)bh * HD * SEQ;
  const int b = bh >> 4, h = bh & 15;
  const int srow = t >> 3;        // staging row 0..31 (+32 on pass 2)
  const int sc8 = (t & 7) * 8;    // staging col (8 bf16 = 16B)

  for (int phase = 0; phase < 2; ++phase) {
    const int qt = phase ? (31 - pr) : pr;
    const int q0 = qt * 64;

    // Q A-frags for this wave's 16 rows, straight from global
    short8 qf[2];
#pragma unroll
    for (int s = 0; s < 2; ++s)
      qf[s] = *(const short8*)&Q[baseQK + (size_t)(q0 + wv * 16 + lr) * HD + s * 32 + qd * 8];

    float m_i[4], l_i[4];
    floatx4 oacc[4];
#pragma unroll
    for (int r = 0; r < 4; ++r) { m_i[r] = -1e30f; l_i[r] = 0.f; }
#pragma unroll
    for (int jj = 0; jj < 4; ++jj) oacc[jj] = (floatx4){0.f, 0.f, 0.f, 0.f};

    for (int kt = 0; kt <= qt; ++kt) {
      const int k0 = kt * 64;
      __syncthreads();  // protect Ks/Vs from previous iteration's readers
#pragma unroll
      for (int p = 0; p < 2; ++p) {
        const int row = srow + p * 32;
        *(uint4*)&Ks[row][sc8] = *(const uint4*)&Kg[baseQK + (size_t)(k0 + row) * HD + sc8];
        *(uint4*)&Vs[row][sc8] = *(const uint4*)&Vg[baseV + (size_t)row * SEQ + k0 + sc8];
      }
      __syncthreads();

      // S tile: 16 q rows x 64 keys per wave (4 col-tiles)
      floatx4 sv[4];
#pragma unroll
      for (int jj = 0; jj < 4; ++jj) sv[jj] = (floatx4){0.f, 0.f, 0.f, 0.f};
#pragma unroll
      for (int s = 0; s < 2; ++s)
#pragma unroll
        for (int jj = 0; jj < 4; ++jj) {
          short8 kf = *(const short8*)&Ks[jj * 16 + lr][s * 32 + qd * 8];
          sv[jj] = __builtin_amdgcn_mfma_f32_16x16x32_bf16(qf[s], kf, sv[jj], 0, 0, 0);
        }

      if (kt == qt) {  // causal mask on the diagonal tile (q0 == k0)
#pragma unroll
        for (int jj = 0; jj < 4; ++jj)
#pragma unroll
          for (int r = 0; r < 4; ++r)
            if (jj * 16 + lr > wv * 16 + qd * 4 + r) sv[jj][r] = -1e30f;
      }

      // online softmax; C/D row = qd*4+r, col = jj*16+lr (reduce over 16-lane group)
#pragma unroll
      for (int r = 0; r < 4; ++r) {
        float rm = fmaxf(fmaxf(sv[0][r], sv[1][r]), fmaxf(sv[2][r], sv[3][r]));
        rm = fmaxf(rm, __shfl_xor(rm, 1, 64));
        rm = fmaxf(rm, __shfl_xor(rm, 2, 64));
        rm = fmaxf(rm, __shfl_xor(rm, 4, 64));
        rm = fmaxf(rm, __shfl_xor(rm, 8, 64));
        const float mn = fmaxf(m_i[r], rm);
        const float alpha = __expf(m_i[r] - mn);
        m_i[r] = mn;
        float rs = 0.f;
#pragma unroll
        for (int jj = 0; jj < 4; ++jj) {
          const float pp = __expf(sv[jj][r] - mn);
          Ps[wv][qd * 4 + r][jj * 16 + lr] = f2bf(pp);
          rs += pp;
        }
        rs += __shfl_xor(rs, 1, 64);
        rs += __shfl_xor(rs, 2, 64);
        rs += __shfl_xor(rs, 4, 64);
        rs += __shfl_xor(rs, 8, 64);
        l_i[r] = l_i[r] * alpha + rs;
#pragma unroll
        for (int jj = 0; jj < 4; ++jj) oacc[jj][r] *= alpha;
      }

      // PV: A = Ps (per-wave, in-wave RAW handled by compiler waitcnt), B = Vs^T frags
#pragma unroll
      for (int s = 0; s < 2; ++s) {
        short8 pf = *(const short8*)&Ps[wv][lr][s * 32 + qd * 8];
#pragma unroll
        for (int jj = 0; jj < 4; ++jj) {
          short8 vf = *(const short8*)&Vs[jj * 16 + lr][s * 32 + qd * 8];
          oacc[jj] = __builtin_amdgcn_mfma_f32_16x16x32_bf16(pf, vf, oacc[jj], 0, 0, 0);
        }
      }
    }

    // epilogue: O[b, s=q, h*64 + d] bf16
#pragma unroll
    for (int r = 0; r < 4; ++r) {
      const int q = q0 + wv * 16 + qd * 4 + r;
      const float inv = 1.f / l_i[r];
#pragma unroll
      for (int jj = 0; jj < 4; ++jj)
        O[(size_t)(b * SEQ + q) * D_MODEL + h * HD + jj * 16 + lr] = f2bf(oacc[jj][r] * inv);
    }
  }
}

extern "C" void kernel_launch(void* const* d_in, const int* in_sizes, int n_in,
                              void* d_out, int out_size, void* d_ws, size_t ws_size,
                              hipStream_t stream) {
  const float* x  = (const float*)d_in[0];
  const float* Wq = (const float*)d_in[1];
  const float* Wk = (const float*)d_in[2];
  const float* Wv = (const float*)d_in[3];
  const float* Wo = (const float*)d_in[4];
  float* out = (float*)d_out;

  // workspace layout (~50 MB, all u16)
  u16* xb = (u16*)d_ws;            // x bf16        [4096,1024]
  u16* wqkv = xb + 4194304;        // Wq|Wk|Wv bf16 [3072,1024]
  u16* wo = wqkv + 3145728;        // Wo bf16       [1024,1024]
  u16* qb = wo + 1048576;          // Q bf16 [B,H,S,HD]
  u16* kb = qb + 4194304;          // K bf16 [B,H,S,HD]
  u16* vb = kb + 4194304;          // V bf16 [B,H,HD,S] (transposed)
  u16* ow = vb + 4194304;          // O bf16 [B,S,D]

  cvt_kernel<<<4096, 256, 0, stream>>>(x, xb, 1048576);
  cvt_kernel<<<1024, 256, 0, stream>>>(Wq, wqkv, 262144);
  cvt_kernel<<<1024, 256, 0, stream>>>(Wk, wqkv + 1048576, 262144);
  cvt_kernel<<<1024, 256, 0, stream>>>(Wv, wqkv + 2097152, 262144);
  cvt_kernel<<<1024, 256, 0, stream>>>(Wo, wo, 262144);

  gemm_bf16_nt<1><<<dim3(24, 32), 256, 0, stream>>>(xb, wqkv, nullptr, qb, kb, vb, MROWS, 3072, 1024);
  rope_kernel<<<32768, 256, 0, stream>>>(qb, kb);
  flash_mfma<<<dim3(16, 32), 256, 0, stream>>>(qb, kb, vb, ow);
  gemm_bf16_nt<0><<<dim3(8, 32), 256, 0, stream>>>(ow, wo, out, nullptr, nullptr, nullptr, MROWS, 1024, 1024);
}

// Round 3
// 267.384 us; speedup vs baseline: 8.2489x; 1.4024x over previous
//
#include <hip/hip_runtime.h>

typedef unsigned short u16;
typedef __attribute__((ext_vector_type(8))) short short8;
typedef __attribute__((ext_vector_type(4))) float floatx4;

#define D_MODEL 1024
#define NHEADS 16
#define HD 64
#define BATCH 2
#define SEQ 2048
#define MROWS (BATCH * SEQ)  // 4096

static __device__ __forceinline__ u16 f2bf(float f) {
  unsigned int u = __float_as_uint(f);
  u += 0x7fffu + ((u >> 16) & 1u);  // round-to-nearest-even
  return (u16)(u >> 16);
}
static __device__ __forceinline__ float bf2f(u16 u) {
  return __uint_as_float(((unsigned int)u) << 16);
}

// ---------------- fp32 -> bf16 convert (vectorized x4) ----------------
__global__ void cvt_kernel(const float* __restrict__ src, u16* __restrict__ dst, int n4) {
  int i = blockIdx.x * 256 + threadIdx.x;
  if (i < n4) {
    float4 v = ((const float4*)src)[i];
    ushort4 o;
    o.x = f2bf(v.x); o.y = f2bf(v.y); o.z = f2bf(v.z); o.w = f2bf(v.w);
    ((ushort4*)dst)[i] = o;
  }
}

// ---------------- bf16 MFMA NT-GEMM: C[M,N] = A[M,K] * B[N,K]^T ----------------
// m97-style K-loop: barrier -> global_load_lds x4 -> barrier(vmcnt drain) -> frags+MFMA.
// LDS unpadded [128][32] u16 (global_load_lds dest is wave-uniform base + lane*16B).
// MODE 0: plain fp32 store to fo[M,N]
// MODE 1: QKV scatter (bf16): Q,K -> [B,H,S,HD]; V -> [B,H,HD,S] (ushort4 stores)
template <int MODE>
__global__ __launch_bounds__(256) void gemm_bf16_nt(
    const u16* __restrict__ A, const u16* __restrict__ B, float* __restrict__ fo,
    u16* __restrict__ qb, u16* __restrict__ kb, u16* __restrict__ vb,
    int M, int N, int K) {
  __shared__ u16 As[128 * 32];
  __shared__ u16 Bs[128 * 32];
  const int t = threadIdx.x;
  const int lane = t & 63;
  const int wv = t >> 6;
  const int wr = wv >> 1, wc = wv & 1;  // wave covers 64x64 quadrant
  const int m0 = blockIdx.y * 128, n0 = blockIdx.x * 128;
  const int qd = lane >> 4, lr = lane & 15;
  // async staging: segment seg = wv*2+i covers rows [seg*16, seg*16+16); lane l
  // writes LDS bytes seg*1024 + l*16 == row (seg*16 + l/4), in-row bytes (l&3)*16.
  const int arow = lane >> 2;
  const int acol = (lane & 3) * 8;  // u16 offset in the 32-u16 row

  floatx4 acc[4][4];
#pragma unroll
  for (int i = 0; i < 4; ++i)
#pragma unroll
    for (int j = 0; j < 4; ++j) acc[i][j] = (floatx4){0.f, 0.f, 0.f, 0.f};

  for (int kt = 0; kt < K; kt += 32) {
    __syncthreads();  // prev iteration's readers done before overwrite
#pragma unroll
    for (int i = 0; i < 2; ++i) {
      const int seg = wv * 2 + i;
      const u16* ga = &A[(size_t)(m0 + seg * 16 + arow) * K + kt + acol];
      const u16* gb = &B[(size_t)(n0 + seg * 16 + arow) * K + kt + acol];
      __builtin_amdgcn_global_load_lds(
          (const __attribute__((address_space(1))) void*)ga,
          (__attribute__((address_space(3))) void*)&As[seg * 512], 16, 0, 0);
      __builtin_amdgcn_global_load_lds(
          (const __attribute__((address_space(1))) void*)gb,
          (__attribute__((address_space(3))) void*)&Bs[seg * 512], 16, 0, 0);
    }
    __syncthreads();  // compiler emits s_waitcnt vmcnt(0) before s_barrier

    short8 af[4], bfr[4];
#pragma unroll
    for (int i = 0; i < 4; ++i)
      af[i] = *(const short8*)&As[(wr * 64 + i * 16 + lr) * 32 + qd * 8];
#pragma unroll
    for (int j = 0; j < 4; ++j)
      bfr[j] = *(const short8*)&Bs[(wc * 64 + j * 16 + lr) * 32 + qd * 8];
#pragma unroll
    for (int i = 0; i < 4; ++i)
#pragma unroll
      for (int j = 0; j < 4; ++j)
        acc[i][j] = __builtin_amdgcn_mfma_f32_16x16x32_bf16(af[i], bfr[j], acc[i][j], 0, 0, 0);
  }

#pragma unroll
  for (int i = 0; i < 4; ++i) {
#pragma unroll
    for (int j = 0; j < 4; ++j) {
      const int n = n0 + wc * 64 + j * 16 + lr;  // C/D: col=lane&15
      const int mb = m0 + wr * 64 + i * 16 + qd * 4;  // + r
      if (MODE == 0) {
#pragma unroll
        for (int r = 0; r < 4; ++r) fo[(size_t)(mb + r) * N + n] = acc[i][j][r];
      } else {
        const int tn = n >> 10, nn = n & 1023;     // uniform per block
        const int h = nn >> 6, d = nn & 63;
        const int b = mb >> 11, s = mb & 2047;     // uniform across r
        const size_t bh = (size_t)(b * NHEADS + h);
        if (tn == 2) {
          ushort4 o;
          o.x = f2bf(acc[i][j][0]); o.y = f2bf(acc[i][j][1]);
          o.z = f2bf(acc[i][j][2]); o.w = f2bf(acc[i][j][3]);
          *(ushort4*)&vb[(bh * HD + d) * SEQ + s] = o;  // 4 consecutive s
        } else {
          u16* dst = (tn == 0) ? qb : kb;
#pragma unroll
          for (int r = 0; r < 4; ++r)
            dst[(bh * SEQ + s + r) * HD + d] = f2bf(acc[i][j][r]);
        }
      }
    }
  }
}

// ---------------- RoPE in-place on bf16 [B,H,S,HD]; one wave per row ----------------
// Q rows additionally scaled by 1/sqrt(HD) = 0.125
__global__ void rope_kernel(u16* __restrict__ qb, u16* __restrict__ kb) {
  const int rid = blockIdx.x * 4 + (threadIdx.x >> 6);  // 0..131071
  const int lane = threadIdx.x & 63;
  u16* base = (rid < 65536) ? qb : kb;
  const float scale = (rid < 65536) ? 0.125f : 1.0f;
  const int r = rid & 65535;
  const int s = r & (SEQ - 1);
  u16* p = base + (size_t)r * HD + lane;
  const int fi = lane & 31;
  const float inv = expf(-(float)fi * 0.28782313662425574f);  // 10000^(-fi/32)
  const float th = (float)s * inv;
  float sn, c;
  sincosf(th, &sn, &c);
  const float v = bf2f(*p);
  const float pv = __shfl_xor(v, 32, 64);  // partner d^32 within the wave
  *p = f2bf((v * c + ((lane < 32) ? -pv : pv) * sn) * scale);
}

// ---------------- causal flash attention, bf16 MFMA ----------------
// grid: (pair=16, bh=32); block 256 (4 waves). Block p handles q-tiles p and 31-p.
// Q,K: [B,H,S,HD] bf16 (rope'd, Q pre-scaled). V: [B,H,HD,S] bf16 (transposed).
__global__ __launch_bounds__(256, 2) void flash_mfma(
    const u16* __restrict__ Q, const u16* __restrict__ Kg,
    const u16* __restrict__ Vg, u16* __restrict__ O) {
  __shared__ u16 Ks[64][72];
  __shared__ u16 Vs[64][72];
  __shared__ u16 Ps[4][16][72];
  const int t = threadIdx.x;
  const int lane = t & 63, wv = t >> 6;
  const int lr = lane & 15, qd = lane >> 4;
  const int bh = blockIdx.y;
  const int pr = blockIdx.x;
  const size_t baseQK = (size_t)bh * SEQ * HD;
  const size_t baseV = (size_t)bh * HD * SEQ;
  const int b = bh >> 4, h = bh & 15;
  const int srow = t >> 3;
  const int sc8 = (t & 7) * 8;

  for (int phase = 0; phase < 2; ++phase) {
    const int qt = phase ? (31 - pr) : pr;
    const int q0 = qt * 64;

    short8 qf[2];
#pragma unroll
    for (int s = 0; s < 2; ++s)
      qf[s] = *(const short8*)&Q[baseQK + (size_t)(q0 + wv * 16 + lr) * HD + s * 32 + qd * 8];

    float m_i[4], l_i[4];
    floatx4 oacc[4];
#pragma unroll
    for (int r = 0; r < 4; ++r) { m_i[r] = -1e30f; l_i[r] = 0.f; }
#pragma unroll
    for (int jj = 0; jj < 4; ++jj) oacc[jj] = (floatx4){0.f, 0.f, 0.f, 0.f};

    for (int kt = 0; kt <= qt; ++kt) {
      const int k0 = kt * 64;
      __syncthreads();
#pragma unroll
      for (int p = 0; p < 2; ++p) {
        const int row = srow + p * 32;
        *(uint4*)&Ks[row][sc8] = *(const uint4*)&Kg[baseQK + (size_t)(k0 + row) * HD + sc8];
        *(uint4*)&Vs[row][sc8] = *(const uint4*)&Vg[baseV + (size_t)row * SEQ + k0 + sc8];
      }
      __syncthreads();

      floatx4 sv[4];
#pragma unroll
      for (int jj = 0; jj < 4; ++jj) sv[jj] = (floatx4){0.f, 0.f, 0.f, 0.f};
#pragma unroll
      for (int s = 0; s < 2; ++s)
#pragma unroll
        for (int jj = 0; jj < 4; ++jj) {
          short8 kf = *(const short8*)&Ks[jj * 16 + lr][s * 32 + qd * 8];
          sv[jj] = __builtin_amdgcn_mfma_f32_16x16x32_bf16(qf[s], kf, sv[jj], 0, 0, 0);
        }

      if (kt == qt) {
#pragma unroll
        for (int jj = 0; jj < 4; ++jj)
#pragma unroll
          for (int r = 0; r < 4; ++r)
            if (jj * 16 + lr > wv * 16 + qd * 4 + r) sv[jj][r] = -1e30f;
      }

#pragma unroll
      for (int r = 0; r < 4; ++r) {
        float rm = fmaxf(fmaxf(sv[0][r], sv[1][r]), fmaxf(sv[2][r], sv[3][r]));
        rm = fmaxf(rm, __shfl_xor(rm, 1, 64));
        rm = fmaxf(rm, __shfl_xor(rm, 2, 64));
        rm = fmaxf(rm, __shfl_xor(rm, 4, 64));
        rm = fmaxf(rm, __shfl_xor(rm, 8, 64));
        const float mn = fmaxf(m_i[r], rm);
        const float alpha = __expf(m_i[r] - mn);
        m_i[r] = mn;
        float rs = 0.f;
#pragma unroll
        for (int jj = 0; jj < 4; ++jj) {
          const float pp = __expf(sv[jj][r] - mn);
          Ps[wv][qd * 4 + r][jj * 16 + lr] = f2bf(pp);
          rs += pp;
        }
        rs += __shfl_xor(rs, 1, 64);
        rs += __shfl_xor(rs, 2, 64);
        rs += __shfl_xor(rs, 4, 64);
        rs += __shfl_xor(rs, 8, 64);
        l_i[r] = l_i[r] * alpha + rs;
#pragma unroll
        for (int jj = 0; jj < 4; ++jj) oacc[jj][r] *= alpha;
      }

#pragma unroll
      for (int s = 0; s < 2; ++s) {
        short8 pf = *(const short8*)&Ps[wv][lr][s * 32 + qd * 8];
#pragma unroll
        for (int jj = 0; jj < 4; ++jj) {
          short8 vf = *(const short8*)&Vs[jj * 16 + lr][s * 32 + qd * 8];
          oacc[jj] = __builtin_amdgcn_mfma_f32_16x16x32_bf16(pf, vf, oacc[jj], 0, 0, 0);
        }
      }
    }

#pragma unroll
    for (int r = 0; r < 4; ++r) {
      const int q = q0 + wv * 16 + qd * 4 + r;
      const float inv = 1.f / l_i[r];
#pragma unroll
      for (int jj = 0; jj < 4; ++jj)
        O[(size_t)(b * SEQ + q) * D_MODEL + h * HD + jj * 16 + lr] = f2bf(oacc[jj][r] * inv);
    }
  }
}

extern "C" void kernel_launch(void* const* d_in, const int* in_sizes, int n_in,
                              void* d_out, int out_size, void* d_ws, size_t ws_size,
                              hipStream_t stream) {
  const float* x  = (const float*)d_in[0];
  const float* Wq = (const float*)d_in[1];
  const float* Wk = (const float*)d_in[2];
  const float* Wv = (const float*)d_in[3];
  const float* Wo = (const float*)d_in[4];
  float* out = (float*)d_out;

  u16* xb = (u16*)d_ws;            // x bf16        [4096,1024]
  u16* wqkv = xb + 4194304;        // Wq|Wk|Wv bf16 [3072,1024]
  u16* wo = wqkv + 3145728;        // Wo bf16       [1024,1024]
  u16* qb = wo + 1048576;          // Q bf16 [B,H,S,HD]
  u16* kb = qb + 4194304;          // K bf16 [B,H,S,HD]
  u16* vb = kb + 4194304;          // V bf16 [B,H,HD,S] (transposed)
  u16* ow = vb + 4194304;          // O bf16 [B,S,D]

  cvt_kernel<<<4096, 256, 0, stream>>>(x, xb, 1048576);
  cvt_kernel<<<1024, 256, 0, stream>>>(Wq, wqkv, 262144);
  cvt_kernel<<<1024, 256, 0, stream>>>(Wk, wqkv + 1048576, 262144);
  cvt_kernel<<<1024, 256, 0, stream>>>(Wv, wqkv + 2097152, 262144);
  cvt_kernel<<<1024, 256, 0, stream>>>(Wo, wo, 262144);

  gemm_bf16_nt<1><<<dim3(24, 32), 256, 0, stream>>>(xb, wqkv, nullptr, qb, kb, vb, MROWS, 3072, 1024);
  rope_kernel<<<32768, 256, 0, stream>>>(qb, kb);
  flash_mfma<<<dim3(16, 32), 256, 0, stream>>>(qb, kb, vb, ow);
  gemm_bf16_nt<0><<<dim3(8, 32), 256, 0, stream>>>(ow, wo, out, nullptr, nullptr, nullptr, MROWS, 1024, 1024);
}